// Round 3
// baseline (23.149 us; speedup 1.0000x reference)
//
#include <hip/hip_runtime.h>
#include <math.h>

// MultiBiasEncoder, two-phase coefficient factorization.
//   out[p,c] = sum_s A_s[p]*w[s,c] + sum_s B_s[p]*k[s,c] + sum_l lwn_l[p]*le[l,c] + cnst[p]
// K1: one thread per position computes the 24 coefficients (all transcendentals),
//     packed as 6 float4 chunks, SoA-by-chunk -> coalesced stores, s_load-able reads.
// K2: lane = channel; coefs arrive via uniform-address float4 loads (SMEM pipe),
//     25 FMAs per output element.

#define EPS_W 1e-6f
#define LN_EPS 1e-5f

constexpr int L = 5;
constexpr int S = 9;
constexpr int C = 64;
constexpr int PPW = 8;  // K2: positions per wave

__device__ __forceinline__ float fastrcp(float v) { return __builtin_amdgcn_rcpf(v); }

// ---------------- K1: coefficients ----------------
__global__ __launch_bounds__(64) void mbe_coef_kernel(
    const float* __restrict__ x,
    const float* __restrict__ ws,
    const float* __restrict__ bs,
    const float* __restrict__ scales,
    const float* __restrict__ locs,
    float4* __restrict__ cw4,   // [6][npos] float4 chunks
    int npos)
{
    const int lane = threadIdx.x;

    // per-lane tables (lane == channel for the stats reduction)
    float w[S], k[S], rsc[S], lc[L];
    float mw[S], mk[S], vw[S], cwk2[S], vk[S];
#pragma unroll
    for (int s = 0; s < S; ++s) {
        float sc = scales[s];
        rsc[s] = fastrcp(sc);
        w[s] = ws[s * C + lane];
        k[s] = bs[s * C + lane] * sc;
    }
#pragma unroll
    for (int l = 0; l < L; ++l) lc[l] = locs[l];

    // wave-wide LN stats per s (closed-form coefficients), one-pass butterfly
#pragma unroll
    for (int s = 0; s < S; ++s) {
        float a0 = w[s], a1 = k[s];
        float a2 = w[s] * w[s], a3 = w[s] * k[s], a4 = k[s] * k[s];
#pragma unroll
        for (int off = 32; off; off >>= 1) {
            a0 += __shfl_xor(a0, off);
            a1 += __shfl_xor(a1, off);
            a2 += __shfl_xor(a2, off);
            a3 += __shfl_xor(a3, off);
            a4 += __shfl_xor(a4, off);
        }
        float mww = a0 * (1.0f / 64.0f);
        float mkk = a1 * (1.0f / 64.0f);
        mw[s] = mww;
        mk[s] = mkk;
        vw[s] = fmaf(-mww, mww, a2 * (1.0f / 64.0f));
        cwk2[s] = 2.0f * fmaf(-mww, mkk, a3 * (1.0f / 64.0f));
        vk[s] = fmaf(-mkk, mkk, a4 * (1.0f / 64.0f));
    }

    // one position per lane — full utilization
    const int p = blockIdx.x * 64 + lane;
    if (p >= npos) return;
    float xv = x[p];

    float d[L], lwv[L];
    float lwsum = 0.0f;
#pragma unroll
    for (int l = 0; l < L; ++l) {
        d[l] = xv - lc[l];
        float ad = fabsf(d[l]);
        lwv[l] = fastrcp(__logf(ad + 1.0f) + EPS_W);
        lwsum += lwv[l];
    }
    float rlw = fastrcp(lwsum);

    float cf[24];
#pragma unroll
    for (int j = 0; j < 24; ++j) cf[j] = 0.0f;

#pragma unroll
    for (int l = 0; l < L; ++l) {
        float dd = d[l];
        float ad = fabsf(dd);
        float lwn = lwv[l] * rlw;
        cf[18 + l] = lwn;

        float swv[S];
        float ssum = 0.0f;
#pragma unroll
        for (int s = 0; s < S; ++s) {
            float t = fabsf(__logf(fmaf(ad, rsc[s], EPS_W))) + EPS_W;
            swv[s] = fastrcp(t);
            ssum += swv[s];
        }
        float rss = fastrcp(ssum) * lwn;

#pragma unroll
        for (int s = 0; s < S; ++s) {
            float mean = fmaf(dd, mw[s], mk[s]);
            float var = fmaf(dd, fmaf(dd, vw[s], cwk2[s]), vk[s]);
            float rstd = rsqrtf(var + LN_EPS);
            float alpha = swv[s] * rss * rstd;
            cf[s] = fmaf(alpha, dd, cf[s]);          // A_s
            cf[9 + s] += alpha;                       // B_s
            cf[23] = fmaf(-alpha, mean, cf[23]);      // const
        }
    }

    // 6 coalesced float4 stores, chunk-SoA layout
#pragma unroll
    for (int j4 = 0; j4 < 6; ++j4) {
        cw4[j4 * npos + p] = make_float4(cf[4 * j4], cf[4 * j4 + 1],
                                         cf[4 * j4 + 2], cf[4 * j4 + 3]);
    }
}

// ---------------- K2: apply ----------------
__global__ __launch_bounds__(256) void mbe_apply_kernel(
    const float* __restrict__ ws,
    const float* __restrict__ bs,
    const float* __restrict__ loc_emb,
    const float* __restrict__ scales,
    const float4* __restrict__ cw4,
    float* __restrict__ out,
    int npos)
{
    const int lane = threadIdx.x & 63;  // == channel
    const int wid = threadIdx.x >> 6;

    float w[S], k[S], le[L];
#pragma unroll
    for (int s = 0; s < S; ++s) {
        w[s] = ws[s * C + lane];
        k[s] = bs[s * C + lane] * scales[s];
    }
#pragma unroll
    for (int l = 0; l < L; ++l) le[l] = loc_emb[l * C + lane];

    const int pbase = (blockIdx.x * 4 + wid) * PPW;
    if (pbase >= npos) return;

    if (pbase + PPW <= npos) {
#pragma unroll
        for (int i = 0; i < PPW; ++i) {
            const int up = __builtin_amdgcn_readfirstlane(pbase + i);
            float4 q0 = cw4[0 * npos + up];
            float4 q1 = cw4[1 * npos + up];
            float4 q2 = cw4[2 * npos + up];
            float4 q3 = cw4[3 * npos + up];
            float4 q4 = cw4[4 * npos + up];
            float4 q5 = cw4[5 * npos + up];
            // layout: A[0..8]=q0.xyzw q1.xyzw q2.x ; B[0..8]=q2.yzw q3.xyzw q4.xy
            //         lwn[0..4]=q4.zw q5.xyz ; cnst=q5.w
            float acc = q5.w;
            acc = fmaf(q0.x, w[0], acc); acc = fmaf(q0.y, w[1], acc);
            acc = fmaf(q0.z, w[2], acc); acc = fmaf(q0.w, w[3], acc);
            acc = fmaf(q1.x, w[4], acc); acc = fmaf(q1.y, w[5], acc);
            acc = fmaf(q1.z, w[6], acc); acc = fmaf(q1.w, w[7], acc);
            acc = fmaf(q2.x, w[8], acc);
            acc = fmaf(q2.y, k[0], acc); acc = fmaf(q2.z, k[1], acc);
            acc = fmaf(q2.w, k[2], acc); acc = fmaf(q3.x, k[3], acc);
            acc = fmaf(q3.y, k[4], acc); acc = fmaf(q3.z, k[5], acc);
            acc = fmaf(q3.w, k[6], acc); acc = fmaf(q4.x, k[7], acc);
            acc = fmaf(q4.y, k[8], acc);
            acc = fmaf(q4.z, le[0], acc); acc = fmaf(q4.w, le[1], acc);
            acc = fmaf(q5.x, le[2], acc); acc = fmaf(q5.y, le[3], acc);
            acc = fmaf(q5.z, le[4], acc);
            out[(size_t)(pbase + i) * C + lane] = acc;
        }
    } else {
        for (int i = 0; i < PPW; ++i) {
            const int p = pbase + i;
            if (p >= npos) break;
            const int up = __builtin_amdgcn_readfirstlane(p);
            float4 q0 = cw4[0 * npos + up];
            float4 q1 = cw4[1 * npos + up];
            float4 q2 = cw4[2 * npos + up];
            float4 q3 = cw4[3 * npos + up];
            float4 q4 = cw4[4 * npos + up];
            float4 q5 = cw4[5 * npos + up];
            float acc = q5.w;
            acc = fmaf(q0.x, w[0], acc); acc = fmaf(q0.y, w[1], acc);
            acc = fmaf(q0.z, w[2], acc); acc = fmaf(q0.w, w[3], acc);
            acc = fmaf(q1.x, w[4], acc); acc = fmaf(q1.y, w[5], acc);
            acc = fmaf(q1.z, w[6], acc); acc = fmaf(q1.w, w[7], acc);
            acc = fmaf(q2.x, w[8], acc);
            acc = fmaf(q2.y, k[0], acc); acc = fmaf(q2.z, k[1], acc);
            acc = fmaf(q2.w, k[2], acc); acc = fmaf(q3.x, k[3], acc);
            acc = fmaf(q3.y, k[4], acc); acc = fmaf(q3.z, k[5], acc);
            acc = fmaf(q3.w, k[6], acc); acc = fmaf(q4.x, k[7], acc);
            acc = fmaf(q4.y, k[8], acc);
            acc = fmaf(q4.z, le[0], acc); acc = fmaf(q4.w, le[1], acc);
            acc = fmaf(q5.x, le[2], acc); acc = fmaf(q5.y, le[3], acc);
            acc = fmaf(q5.z, le[4], acc);
            out[(size_t)p * C + lane] = acc;
        }
    }
}

extern "C" void kernel_launch(void* const* d_in, const int* in_sizes, int n_in,
                              void* d_out, int out_size, void* d_ws, size_t ws_size,
                              hipStream_t stream) {
    const float* x = (const float*)d_in[0];
    const float* ws = (const float*)d_in[1];
    const float* bs = (const float*)d_in[2];
    const float* loc_emb = (const float*)d_in[3];
    const float* scales = (const float*)d_in[4];
    const float* locs = (const float*)d_in[5];
    float* out = (float*)d_out;
    float4* cw4 = (float4*)d_ws;  // 6 * npos float4 = 24 floats/position

    int npos = in_sizes[0];  // B*T = 16384

    int blocks1 = (npos + 63) / 64;  // 256 one-wave blocks, lane = position
    mbe_coef_kernel<<<blocks1, 64, 0, stream>>>(x, ws, bs, scales, locs, cw4, npos);

    int pos_per_block = 4 * PPW;  // 4 waves/block * 8 positions
    int blocks2 = (npos + pos_per_block - 1) / pos_per_block;  // 512
    mbe_apply_kernel<<<blocks2, 256, 0, stream>>>(ws, bs, loc_emb, scales, cw4, out, npos);
}

// Round 4
// 13.392 us; speedup vs baseline: 1.7286x; 1.7286x over previous
//
#include <hip/hip_runtime.h>
#include <math.h>

// MultiBiasEncoder, fused single-kernel, three internal phases.
//   out[p,c] = sum_s A_s[p]*w[s,c] + sum_s B_s[p]*k[s,c] + sum_l lwn_l[p]*le[l,c] + cnst[p]
// Stats (closed-form LN): mean = d*mw+mk ; var = d^2*vw + d*cwk2 + vk.
// Phase S: wave w butterflies stats for s = w, w+4, (8)  -> LDS  (~450 cy wall)
// Phase A: wave 0, lane = position; computes 24 coefs/position -> LDS
//          scale-log factorized: log(|d|/s+eps) ~= max(log|d| - log s, log eps)
// Phase B: all 4 waves, 16 pos each; 6 broadcast float4 LDS reads + 25 FMA; coalesced store.

#define EPS_W 1e-6f
#define LN_EPS 1e-5f
#define LOG_EPS -13.815511f   // ln(1e-6)

constexpr int L = 5;
constexpr int S = 9;
constexpr int C = 64;
constexpr int POS = 64;   // positions per block

__device__ __forceinline__ float fastrcp(float v) { return __builtin_amdgcn_rcpf(v); }

__global__ __launch_bounds__(256, 1) void mbe3_kernel(
    const float* __restrict__ x,
    const float* __restrict__ ws,
    const float* __restrict__ bs,
    const float* __restrict__ loc_emb,
    const float* __restrict__ scales,
    const float* __restrict__ locs,
    float* __restrict__ out,
    int npos)
{
    const int tid = threadIdx.x;
    const int lane = tid & 63;
    const int wid = tid >> 6;

    __shared__ float stats[S][8];        // mw, mk, vw, cwk2, vk, log(scale), pad, pad
    __shared__ float4 coefLds[POS][6];   // 24 coefs per position

    // ---- per-thread tables (lane == channel) ----
    float w[S], k[S], le[L];
#pragma unroll
    for (int s = 0; s < S; ++s) {
        w[s] = ws[s * C + lane];
        k[s] = bs[s * C + lane] * scales[s];
    }
#pragma unroll
    for (int l = 0; l < L; ++l) le[l] = loc_emb[l * C + lane];

    // ---- Phase S: distributed LN-stat butterflies ----
    for (int s = wid; s < S; s += 4) {
        float a0 = w[s], a1 = k[s];
        float a2 = w[s] * w[s], a3 = w[s] * k[s], a4 = k[s] * k[s];
#pragma unroll
        for (int off = 32; off; off >>= 1) {
            a0 += __shfl_xor(a0, off);
            a1 += __shfl_xor(a1, off);
            a2 += __shfl_xor(a2, off);
            a3 += __shfl_xor(a3, off);
            a4 += __shfl_xor(a4, off);
        }
        if (lane == 0) {
            float mww = a0 * (1.0f / 64.0f);
            float mkk = a1 * (1.0f / 64.0f);
            stats[s][0] = mww;
            stats[s][1] = mkk;
            stats[s][2] = fmaf(-mww, mww, a2 * (1.0f / 64.0f));          // vw
            stats[s][3] = 2.0f * fmaf(-mww, mkk, a3 * (1.0f / 64.0f));   // cwk2
            stats[s][4] = fmaf(-mkk, mkk, a4 * (1.0f / 64.0f));          // vk
            stats[s][5] = __logf(scales[s]);                             // log(scale)
        }
    }
    __syncthreads();

    // ---- Phase A: wave 0, lane = position ----
    const int pbase = blockIdx.x * POS;
    if (wid == 0) {
        const int p = pbase + lane;
        if (p < npos) {
            // stats -> registers (broadcast LDS reads)
            float mw[S], mk[S], vw[S], c2[S], vk[S], lg[S];
#pragma unroll
            for (int s = 0; s < S; ++s) {
                mw[s] = stats[s][0]; mk[s] = stats[s][1]; vw[s] = stats[s][2];
                c2[s] = stats[s][3]; vk[s] = stats[s][4]; lg[s] = stats[s][5];
            }
            const float xv = x[p];

            float d[L], lwv[L], llog[L];
            float lwsum = 0.0f;
#pragma unroll
            for (int l = 0; l < L; ++l) {
                d[l] = xv - locs[l];
                float ad = fabsf(d[l]);
                lwv[l] = fastrcp(__logf(ad + 1.0f) + EPS_W);
                lwsum += lwv[l];
                llog[l] = __logf(ad);   // -inf at ad=0 is clamped below
            }
            const float rlw = fastrcp(lwsum);

            float cf[24];
#pragma unroll
            for (int j = 0; j < 24; ++j) cf[j] = 0.0f;

#pragma unroll
            for (int l = 0; l < L; ++l) {
                const float dd = d[l];
                const float d2 = dd * dd;
                const float lwn = lwv[l] * rlw;
                cf[18 + l] = lwn;

                float swv[S];
                float ssum = 0.0f;
#pragma unroll
                for (int s = 0; s < S; ++s) {
                    float u = fmaxf(llog[l] - lg[s], LOG_EPS);  // ~ log(|d|/s + eps)
                    swv[s] = fastrcp(fabsf(u) + EPS_W);
                    ssum += swv[s];
                }
                const float rss = fastrcp(ssum) * lwn;

#pragma unroll
                for (int s = 0; s < S; ++s) {
                    float mean = fmaf(dd, mw[s], mk[s]);
                    float var = fmaf(d2, vw[s], fmaf(dd, c2[s], vk[s]));
                    float rstd = rsqrtf(var + LN_EPS);
                    float alpha = swv[s] * rss * rstd;
                    cf[s] = fmaf(alpha, dd, cf[s]);          // A_s
                    cf[9 + s] += alpha;                       // B_s
                    cf[23] = fmaf(-alpha, mean, cf[23]);      // const
                }
            }

#pragma unroll
            for (int j = 0; j < 6; ++j)
                coefLds[lane][j] = make_float4(cf[4 * j], cf[4 * j + 1],
                                               cf[4 * j + 2], cf[4 * j + 3]);
        }
    }
    __syncthreads();

    // ---- Phase B: all waves; wave wid handles rows wid*16 .. wid*16+15 ----
    const int rbase = wid * 16;
#pragma unroll
    for (int i = 0; i < 16; ++i) {
        const int row = rbase + i;
        const int p = pbase + row;
        if (p >= npos) break;
        float4 q0 = coefLds[row][0];
        float4 q1 = coefLds[row][1];
        float4 q2 = coefLds[row][2];
        float4 q3 = coefLds[row][3];
        float4 q4 = coefLds[row][4];
        float4 q5 = coefLds[row][5];
        // A[0..8]=q0.xyzw q1.xyzw q2.x ; B[0..8]=q2.yzw q3.xyzw q4.xy
        // lwn[0..4]=q4.zw q5.xyz ; cnst=q5.w
        float acc = q5.w;
        acc = fmaf(q0.x, w[0], acc); acc = fmaf(q0.y, w[1], acc);
        acc = fmaf(q0.z, w[2], acc); acc = fmaf(q0.w, w[3], acc);
        acc = fmaf(q1.x, w[4], acc); acc = fmaf(q1.y, w[5], acc);
        acc = fmaf(q1.z, w[6], acc); acc = fmaf(q1.w, w[7], acc);
        acc = fmaf(q2.x, w[8], acc);
        acc = fmaf(q2.y, k[0], acc); acc = fmaf(q2.z, k[1], acc);
        acc = fmaf(q2.w, k[2], acc); acc = fmaf(q3.x, k[3], acc);
        acc = fmaf(q3.y, k[4], acc); acc = fmaf(q3.z, k[5], acc);
        acc = fmaf(q3.w, k[6], acc); acc = fmaf(q4.x, k[7], acc);
        acc = fmaf(q4.y, k[8], acc);
        acc = fmaf(q4.z, le[0], acc); acc = fmaf(q4.w, le[1], acc);
        acc = fmaf(q5.x, le[2], acc); acc = fmaf(q5.y, le[3], acc);
        acc = fmaf(q5.z, le[4], acc);
        out[(size_t)p * C + lane] = acc;
    }
}

extern "C" void kernel_launch(void* const* d_in, const int* in_sizes, int n_in,
                              void* d_out, int out_size, void* d_ws, size_t ws_size,
                              hipStream_t stream) {
    const float* x = (const float*)d_in[0];
    const float* ws = (const float*)d_in[1];
    const float* bs = (const float*)d_in[2];
    const float* loc_emb = (const float*)d_in[3];
    const float* scales = (const float*)d_in[4];
    const float* locs = (const float*)d_in[5];
    float* out = (float*)d_out;

    int npos = in_sizes[0];  // B*T = 16384
    int blocks = (npos + POS - 1) / POS;  // 256
    mbe3_kernel<<<blocks, 256, 0, stream>>>(x, ws, bs, loc_emb, scales, locs, out, npos);
}

// Round 5
// 12.629 us; speedup vs baseline: 1.8330x; 1.0604x over previous
//
#include <hip/hip_runtime.h>
#include <math.h>

// MultiBiasEncoder, fused single-kernel, wave-independent phases.
//   out[p,c] = sum_s A_s[p]*w[s,c] + sum_s B_s[p]*k[s,c] + sum_l lwn_l[p]*le[l,c] + cnst[p]
// Closed-form LN stats: mean = d*mw+mk ; var = d^2*vw + d*cwk2 + vk.
// Phase S: wave w butterflies stats for s in {w, w+4, w+8} -> LDS; ONE barrier.
// Phase A: EACH wave, lanes 0..15, computes 24 coefs for its own 16 positions -> own LDS region.
//          (same-wave LDS dep: no barrier needed)
// Phase B: each wave applies its own 16 positions; 6 broadcast float4 reads + 25 FMA; coalesced store.
// scale-log factorized: log(|d|/s+eps) ~= max(log|d| - log s, log eps)  (verified R4, absmax 7.8e-3)

#define EPS_W 1e-6f
#define LN_EPS 1e-5f
#define LOG_EPS -13.815511f   // ln(1e-6)

constexpr int L = 5;
constexpr int S = 9;
constexpr int C = 64;
constexpr int PW = 16;    // positions per wave
constexpr int POS = 64;   // positions per block (4 waves)

__device__ __forceinline__ float fastrcp(float v) { return __builtin_amdgcn_rcpf(v); }

__global__ __launch_bounds__(256) void mbe4_kernel(
    const float* __restrict__ x,
    const float* __restrict__ ws,
    const float* __restrict__ bs,
    const float* __restrict__ loc_emb,
    const float* __restrict__ scales,
    const float* __restrict__ locs,
    float* __restrict__ out,
    int npos)
{
    const int tid = threadIdx.x;
    const int lane = tid & 63;
    const int wid = tid >> 6;

    __shared__ float4 statsLds[S][2];    // [s][0]={mw,mk,vw,cwk2} [s][1]={vk,log(scale),-,-}
    __shared__ float4 coefLds[POS][6];   // 24 coefs per position

    const int pbase = blockIdx.x * POS + wid * PW;  // this wave's first position

    // ---- early x prefetch (lanes 0..PW-1 own one position each) ----
    float xv = 0.0f;
    const int myp = pbase + lane;   // valid only for lane < PW
    if (lane < PW && myp < npos) xv = x[myp];

    // ---- per-thread tables (lane == channel) ----
    float w[S], k[S], le[L];
#pragma unroll
    for (int s = 0; s < S; ++s) {
        w[s] = ws[s * C + lane];
        k[s] = bs[s * C + lane] * scales[s];
    }
#pragma unroll
    for (int l = 0; l < L; ++l) le[l] = loc_emb[l * C + lane];

    // ---- Phase S: distributed LN-stat butterflies (wave w: s = w, w+4, w+8) ----
    for (int s = wid; s < S; s += 4) {
        float a0 = w[s], a1 = k[s];
        float a2 = w[s] * w[s], a3 = w[s] * k[s], a4 = k[s] * k[s];
#pragma unroll
        for (int off = 32; off; off >>= 1) {
            a0 += __shfl_xor(a0, off);
            a1 += __shfl_xor(a1, off);
            a2 += __shfl_xor(a2, off);
            a3 += __shfl_xor(a3, off);
            a4 += __shfl_xor(a4, off);
        }
        if (lane == 0) {
            float mww = a0 * (1.0f / 64.0f);
            float mkk = a1 * (1.0f / 64.0f);
            statsLds[s][0] = make_float4(
                mww, mkk,
                fmaf(-mww, mww, a2 * (1.0f / 64.0f)),            // vw
                2.0f * fmaf(-mww, mkk, a3 * (1.0f / 64.0f)));    // cwk2
            statsLds[s][1] = make_float4(
                fmaf(-mkk, mkk, a4 * (1.0f / 64.0f)),            // vk
                __logf(scales[s]), 0.0f, 0.0f);
        }
    }
    __syncthreads();

    // ---- Phase A: lanes 0..PW-1 of EVERY wave; one position per lane ----
    if (lane < PW && myp < npos) {
        float mw[S], mk[S], vw[S], c2[S], vk[S], lg[S];
#pragma unroll
        for (int s = 0; s < S; ++s) {
            float4 a = statsLds[s][0];
            float4 b = statsLds[s][1];
            mw[s] = a.x; mk[s] = a.y; vw[s] = a.z; c2[s] = a.w;
            vk[s] = b.x; lg[s] = b.y;
        }

        float d[L], lwv[L], llog[L];
        float lwsum = 0.0f;
#pragma unroll
        for (int l = 0; l < L; ++l) {
            d[l] = xv - locs[l];
            float ad = fabsf(d[l]);
            lwv[l] = fastrcp(__logf(ad + 1.0f) + EPS_W);
            lwsum += lwv[l];
            llog[l] = __logf(ad);   // -inf at ad=0 is clamped by fmax below
        }
        const float rlw = fastrcp(lwsum);

        float cf[24];
#pragma unroll
        for (int j = 0; j < 24; ++j) cf[j] = 0.0f;

#pragma unroll
        for (int l = 0; l < L; ++l) {
            const float dd = d[l];
            const float d2 = dd * dd;
            const float lwn = lwv[l] * rlw;
            cf[18 + l] = lwn;

            float swv[S];
            float ssum = 0.0f;
#pragma unroll
            for (int s = 0; s < S; ++s) {
                float u = fmaxf(llog[l] - lg[s], LOG_EPS);  // ~ log(|d|/scale + eps)
                swv[s] = fastrcp(fabsf(u) + EPS_W);
                ssum += swv[s];
            }
            const float rss = fastrcp(ssum) * lwn;

#pragma unroll
            for (int s = 0; s < S; ++s) {
                float mean = fmaf(dd, mw[s], mk[s]);
                float var = fmaf(d2, vw[s], fmaf(dd, c2[s], vk[s]));
                float rstd = rsqrtf(var + LN_EPS);
                float alpha = swv[s] * rss * rstd;
                cf[s] = fmaf(alpha, dd, cf[s]);          // A_s
                cf[9 + s] += alpha;                       // B_s
                cf[23] = fmaf(-alpha, mean, cf[23]);      // const
            }
        }

        const int row = wid * PW + lane;
#pragma unroll
        for (int j = 0; j < 6; ++j)
            coefLds[row][j] = make_float4(cf[4 * j], cf[4 * j + 1],
                                          cf[4 * j + 2], cf[4 * j + 3]);
    }
    // NO __syncthreads: each wave reads only rows it wrote itself (lgkmcnt-ordered).

    // ---- Phase B: each wave applies its own 16 positions ----
#pragma unroll
    for (int i = 0; i < PW; ++i) {
        const int p = pbase + i;
        if (p >= npos) break;
        const int row = wid * PW + i;
        float4 q0 = coefLds[row][0];
        float4 q1 = coefLds[row][1];
        float4 q2 = coefLds[row][2];
        float4 q3 = coefLds[row][3];
        float4 q4 = coefLds[row][4];
        float4 q5 = coefLds[row][5];
        // A[0..8]=q0.xyzw q1.xyzw q2.x ; B[0..8]=q2.yzw q3.xyzw q4.xy
        // lwn[0..4]=q4.zw q5.xyz ; cnst=q5.w
        float acc = q5.w;
        acc = fmaf(q0.x, w[0], acc); acc = fmaf(q0.y, w[1], acc);
        acc = fmaf(q0.z, w[2], acc); acc = fmaf(q0.w, w[3], acc);
        acc = fmaf(q1.x, w[4], acc); acc = fmaf(q1.y, w[5], acc);
        acc = fmaf(q1.z, w[6], acc); acc = fmaf(q1.w, w[7], acc);
        acc = fmaf(q2.x, w[8], acc);
        acc = fmaf(q2.y, k[0], acc); acc = fmaf(q2.z, k[1], acc);
        acc = fmaf(q2.w, k[2], acc); acc = fmaf(q3.x, k[3], acc);
        acc = fmaf(q3.y, k[4], acc); acc = fmaf(q3.z, k[5], acc);
        acc = fmaf(q3.w, k[6], acc); acc = fmaf(q4.x, k[7], acc);
        acc = fmaf(q4.y, k[8], acc);
        acc = fmaf(q4.z, le[0], acc); acc = fmaf(q4.w, le[1], acc);
        acc = fmaf(q5.x, le[2], acc); acc = fmaf(q5.y, le[3], acc);
        acc = fmaf(q5.z, le[4], acc);
        out[(size_t)p * C + lane] = acc;
    }
}

extern "C" void kernel_launch(void* const* d_in, const int* in_sizes, int n_in,
                              void* d_out, int out_size, void* d_ws, size_t ws_size,
                              hipStream_t stream) {
    const float* x = (const float*)d_in[0];
    const float* ws = (const float*)d_in[1];
    const float* bs = (const float*)d_in[2];
    const float* loc_emb = (const float*)d_in[3];
    const float* scales = (const float*)d_in[4];
    const float* locs = (const float*)d_in[5];
    float* out = (float*)d_out;

    int npos = in_sizes[0];  // B*T = 16384
    int blocks = (npos + POS - 1) / POS;  // 256
    mbe4_kernel<<<blocks, 256, 0, stream>>>(x, ws, bs, loc_emb, scales, locs, out, npos);
}